// Round 1
// baseline (929.634 us; speedup 1.0000x reference)
//
#include <hip/hip_runtime.h>
#include <hip/hip_bf16.h>

constexpr int N = 100000;      // nodes
constexpr int E = 1600000;     // edges
constexpr int DIN = 15;
constexpr int DH  = 128;

// ---------------- utility ----------------
__global__ void k_zero_int(int* __restrict__ p, int n) {
    int i = blockIdx.x * blockDim.x + threadIdx.x;
    if (i < n) p[i] = 0;
}

// ---------------- CSR build ----------------
__global__ void k_degree(const int* __restrict__ dst, int* __restrict__ deg) {
    int i = blockIdx.x * blockDim.x + threadIdx.x;
    if (i < E) atomicAdd(&deg[dst[i]], 1);
}

// single block, 1024 threads: exclusive scan of deg -> rowptr, fillpos; deg_inv
__global__ void k_scan(const int* __restrict__ deg, int* __restrict__ rowptr,
                       int* __restrict__ fillpos, float* __restrict__ deg_inv) {
    __shared__ int part[1024];
    const int t = threadIdx.x;
    const int C = (N + 1023) / 1024;           // 98
    const int lo = t * C;
    const int hi = min(lo + C, N);
    int s = 0;
    for (int i = lo; i < hi; ++i) s += deg[i];
    part[t] = s;
    __syncthreads();
    for (int d = 1; d < 1024; d <<= 1) {
        int v = (t >= d) ? part[t - d] : 0;
        __syncthreads();
        part[t] += v;
        __syncthreads();
    }
    int base = (t == 0) ? 0 : part[t - 1];
    for (int i = lo; i < hi; ++i) {
        int v = deg[i];
        rowptr[i]  = base;
        fillpos[i] = base;
        deg_inv[i] = 1.0f / fmaxf((float)v, 1.0f);
        base += v;
    }
    if (t == 1023) rowptr[N] = part[1023];
}

__global__ void k_fill(const int* __restrict__ src, const int* __restrict__ dst,
                       int* __restrict__ fillpos, int* __restrict__ csr) {
    int i = blockIdx.x * blockDim.x + threadIdx.x;
    if (i < E) {
        int d = dst[i];
        int pos = atomicAdd(&fillpos[d], 1);
        csr[pos] = src[i];
    }
}

// ---------------- layer 1 ----------------
// agg1[n][d] = deg_inv[n] * sum_{s in nbr(n)} x[s][d]   (d < 15)
__global__ __launch_bounds__(256) void k_agg1(const int* __restrict__ rowptr,
                                              const int* __restrict__ csr,
                                              const float* __restrict__ x,
                                              const float* __restrict__ deg_inv,
                                              float* __restrict__ agg1) {
    int g = threadIdx.x >> 4;        // 16 rows per block
    int d = threadIdx.x & 15;
    int n = blockIdx.x * 16 + g;
    if (n >= N || d >= DIN) return;
    int lo = rowptr[n], hi = rowptr[n + 1];
    float acc = 0.f;
    for (int i = lo; i < hi; ++i) {
        int s = csr[i];
        acc += x[s * DIN + d];
    }
    agg1[n * DIN + d] = acc * deg_inv[n];
}

// h1[n][j] = relu(agg1[n]·W1l[:,j] + x[n]·W1r[:,j] + b1[j])
__global__ __launch_bounds__(256) void k_h1(const float* __restrict__ x,
                                            const float* __restrict__ agg1,
                                            const float* __restrict__ W1l,
                                            const float* __restrict__ W1r,
                                            const float* __restrict__ b1,
                                            float* __restrict__ h1) {
    __shared__ float sWl[DIN * DH];
    __shared__ float sWr[DIN * DH];
    __shared__ float sb[DH];
    for (int i = threadIdx.x; i < DIN * DH; i += 256) {
        sWl[i] = W1l[i];
        sWr[i] = W1r[i];
    }
    if (threadIdx.x < DH) sb[threadIdx.x] = b1[threadIdx.x];
    __syncthreads();
    int j = threadIdx.x & 127;
    for (int n = blockIdx.x * 2 + (threadIdx.x >> 7); n < N; n += gridDim.x * 2) {
        const float* ar = &agg1[n * DIN];
        const float* xr = &x[n * DIN];
        float acc = sb[j];
#pragma unroll
        for (int k = 0; k < DIN; ++k)
            acc = fmaf(ar[k], sWl[k * DH + j], fmaf(xr[k], sWr[k * DH + j], acc));
        h1[n * DH + j] = fmaxf(acc, 0.f);
    }
}

// ---------------- layer 2 aggregation (SpMM) ----------------
// agg2[n][d] = deg_inv[n] * sum_{s in nbr(n)} h1[s][d]
__global__ __launch_bounds__(256) void k_agg2(const int* __restrict__ rowptr,
                                              const int* __restrict__ csr,
                                              const float* __restrict__ h1,
                                              const float* __restrict__ deg_inv,
                                              float* __restrict__ agg2) {
    int n = blockIdx.x * 2 + (threadIdx.x >> 7);
    int d = threadIdx.x & 127;
    if (n >= N) return;
    int lo = rowptr[n], hi = rowptr[n + 1];
    float acc = 0.f;
    int i = lo;
    for (; i + 1 < hi; i += 2) {
        int s0 = csr[i], s1 = csr[i + 1];
        acc += h1[s0 * DH + d];
        acc += h1[s1 * DH + d];
    }
    if (i < hi) acc += h1[csr[i] * DH + d];
    agg2[n * DH + d] = acc * deg_inv[n];
}

// ---------------- layer 2 GEMM + layer 3 projection ----------------
// per node: h2 = relu(agg2·W2l + h1·W2r + b2); p = h2·W3l; r = h2·W3r
#define NT 32   // nodes per block
#define KT 16   // k-tile
__global__ __launch_bounds__(256) void k_h2pr(const float* __restrict__ agg2,
                                              const float* __restrict__ h1,
                                              const float* __restrict__ W2l,
                                              const float* __restrict__ W2r,
                                              const float* __restrict__ b2,
                                              const float* __restrict__ W3l,
                                              const float* __restrict__ W3r,
                                              float* __restrict__ p,
                                              float* __restrict__ r) {
    __shared__ float sAT[DH][NT + 4];   // [k][n] transposed, padded (16B-aligned rows)
    __shared__ float sHT[DH][NT + 4];
    __shared__ float sWl[KT][DH];
    __shared__ float sWr[KT][DH];
    __shared__ float sW3l[DH], sW3r[DH], sb2[DH];

    const int tid = threadIdx.x;
    const int node0 = blockIdx.x * NT;

    for (int idx = tid; idx < NT * DH; idx += 256) {
        int n = idx >> 7, d = idx & 127;
        sAT[d][n] = agg2[(node0 + n) * DH + d];
        sHT[d][n] = h1[(node0 + n) * DH + d];
    }
    if (tid < DH) {
        sb2[tid]  = b2[tid];
        sW3l[tid] = W3l[tid];
        sW3r[tid] = W3r[tid];
    }

    const int jr = tid & 31;   // column group: cols j0..j0+3
    const int nr = tid >> 5;   // node group: nodes n0..n0+3
    const int j0 = jr * 4;
    const int n0 = nr * 4;

    float acc[4][4] = {{0.f}};   // [node][col]

    for (int kt = 0; kt < DH / KT; ++kt) {
        __syncthreads();
        for (int idx = tid; idx < KT * DH; idx += 256) {
            int kk = idx >> 7, c = idx & 127;
            sWl[kk][c] = W2l[(kt * KT + kk) * DH + c];
            sWr[kk][c] = W2r[(kt * KT + kk) * DH + c];
        }
        __syncthreads();
#pragma unroll
        for (int kk = 0; kk < KT; ++kk) {
            const int k = kt * KT + kk;
            float4 a4 = *(const float4*)&sAT[k][n0];
            float4 h4 = *(const float4*)&sHT[k][n0];
            float4 wl = *(const float4*)&sWl[kk][j0];
            float4 wr = *(const float4*)&sWr[kk][j0];
            const float av[4] = {a4.x, a4.y, a4.z, a4.w};
            const float hv[4] = {h4.x, h4.y, h4.z, h4.w};
            const float wlv[4] = {wl.x, wl.y, wl.z, wl.w};
            const float wrv[4] = {wr.x, wr.y, wr.z, wr.w};
#pragma unroll
            for (int a = 0; a < 4; ++a)
#pragma unroll
                for (int b = 0; b < 4; ++b)
                    acc[a][b] = fmaf(av[a], wlv[b], fmaf(hv[a], wrv[b], acc[a][b]));
        }
    }

    // epilogue: bias + relu + contract with W3l/W3r, reduce over column groups
    float pp[4] = {0.f, 0.f, 0.f, 0.f};
    float rr[4] = {0.f, 0.f, 0.f, 0.f};
#pragma unroll
    for (int a = 0; a < 4; ++a) {
#pragma unroll
        for (int b = 0; b < 4; ++b) {
            float h2v = fmaxf(acc[a][b] + sb2[j0 + b], 0.f);
            pp[a] = fmaf(h2v, sW3l[j0 + b], pp[a]);
            rr[a] = fmaf(h2v, sW3r[j0 + b], rr[a]);
        }
    }
    // reduce across jr (lanes 0..31 within each wave half)
#pragma unroll
    for (int m = 16; m >= 1; m >>= 1) {
#pragma unroll
        for (int a = 0; a < 4; ++a) {
            pp[a] += __shfl_xor(pp[a], m, 64);
            rr[a] += __shfl_xor(rr[a], m, 64);
        }
    }
    if (jr == 0) {
#pragma unroll
        for (int a = 0; a < 4; ++a) {
            p[node0 + n0 + a] = pp[a];
            r[node0 + n0 + a] = rr[a];
        }
    }
}

// ---------------- output ----------------
// out[n] = deg_inv[n] * sum_{s in nbr(n)} p[s] + r[n] + b3
__global__ void k_out(const int* __restrict__ rowptr, const int* __restrict__ csr,
                      const float* __restrict__ p, const float* __restrict__ r,
                      const float* __restrict__ deg_inv, const float* __restrict__ b3,
                      float* __restrict__ out) {
    int n = blockIdx.x * blockDim.x + threadIdx.x;
    if (n >= N) return;
    int lo = rowptr[n], hi = rowptr[n + 1];
    float acc = 0.f;
    for (int i = lo; i < hi; ++i) acc += p[csr[i]];
    out[n] = acc * deg_inv[n] + r[n] + b3[0];
}

// ---------------- host ----------------
extern "C" void kernel_launch(void* const* d_in, const int* in_sizes, int n_in,
                              void* d_out, int out_size, void* d_ws, size_t ws_size,
                              hipStream_t stream) {
    const float* x    = (const float*)d_in[0];
    const int*   eidx = (const int*)d_in[1];   // [2,E] flat: row0=src, row1=dst
    const float* W1l  = (const float*)d_in[2];
    const float* W1r  = (const float*)d_in[3];
    const float* b1   = (const float*)d_in[4];
    const float* W2l  = (const float*)d_in[5];
    const float* W2r  = (const float*)d_in[6];
    const float* b2   = (const float*)d_in[7];
    const float* W3l  = (const float*)d_in[8];
    const float* W3r  = (const float*)d_in[9];
    const float* b3   = (const float*)d_in[10];
    float* out = (float*)d_out;

    const int* srcs = eidx;
    const int* dsts = eidx + E;

    // workspace carve-up (256B aligned)
    size_t off = 0;
    auto alloc = [&](size_t bytes) {
        size_t o = off;
        off = (off + bytes + 255) & ~(size_t)255;
        return o;
    };
    char* w = (char*)d_ws;
    int*   deg_i   = (int*)(w + alloc((size_t)N * 4));
    int*   rowptr  = (int*)(w + alloc((size_t)(N + 1) * 4));
    int*   fillpos = (int*)(w + alloc((size_t)N * 4));
    int*   csr     = (int*)(w + alloc((size_t)E * 4));
    float* deg_inv = (float*)(w + alloc((size_t)N * 4));
    float* agg1    = (float*)(w + alloc((size_t)N * DIN * 4));
    float* h1      = (float*)(w + alloc((size_t)N * DH * 4));
    float* agg2    = (float*)(w + alloc((size_t)N * DH * 4));
    float* pbuf    = (float*)(w + alloc((size_t)N * 4));
    float* rbuf    = (float*)(w + alloc((size_t)N * 4));
    (void)ws_size;

    // 1. CSR build
    k_zero_int<<<(N + 255) / 256, 256, 0, stream>>>(deg_i, N);
    k_degree<<<(E + 255) / 256, 256, 0, stream>>>(dsts, deg_i);
    k_scan<<<1, 1024, 0, stream>>>(deg_i, rowptr, fillpos, deg_inv);
    k_fill<<<(E + 255) / 256, 256, 0, stream>>>(srcs, dsts, fillpos, csr);

    // 2. layer 1
    k_agg1<<<(N + 15) / 16, 256, 0, stream>>>(rowptr, csr, x, deg_inv, agg1);
    k_h1<<<1024, 256, 0, stream>>>(x, agg1, W1l, W1r, b1, h1);

    // 3. layer 2 aggregation
    k_agg2<<<(N + 1) / 2, 256, 0, stream>>>(rowptr, csr, h1, deg_inv, agg2);

    // 4. layer 2 GEMM + layer-3 projection (p = h2·W3l, r = h2·W3r)
    k_h2pr<<<(N + NT - 1) / NT, 256, 0, stream>>>(agg2, h1, W2l, W2r, b2, W3l, W3r,
                                                  pbuf, rbuf);

    // 5. output: scalar aggregation of p
    k_out<<<(N + 255) / 256, 256, 0, stream>>>(rowptr, csr, pbuf, rbuf, deg_inv, b3, out);
}

// Round 2
// 663.605 us; speedup vs baseline: 1.4009x; 1.4009x over previous
//
#include <hip/hip_runtime.h>
#include <hip/hip_bf16.h>

constexpr int N = 100000;      // nodes
constexpr int E = 1600000;     // edges
constexpr int DIN = 15;
constexpr int DH  = 128;

constexpr int SCAN_CHUNK  = 512;                                  // elems per block
constexpr int SCAN_BLOCKS = (N + SCAN_CHUNK - 1) / SCAN_CHUNK;    // 196

// ---------------- utility ----------------
__global__ void k_zero_int(int* __restrict__ p, int n) {
    int i = blockIdx.x * blockDim.x + threadIdx.x;
    if (i < n) p[i] = 0;
}

// ---------------- CSR build ----------------
__global__ void k_degree(const int* __restrict__ dst, int* __restrict__ deg) {
    int i = blockIdx.x * blockDim.x + threadIdx.x;
    if (i < E) atomicAdd(&deg[dst[i]], 1);
}

// phase 1: per-block sum of a 512-element chunk of deg
__global__ __launch_bounds__(256) void k_block_sums(const int* __restrict__ deg,
                                                    int* __restrict__ bsum) {
    __shared__ int red[256];
    const int t = threadIdx.x;
    const int i0 = blockIdx.x * SCAN_CHUNK + t * 2;
    int s = 0;
    if (i0 < N)     s += deg[i0];
    if (i0 + 1 < N) s += deg[i0 + 1];
    red[t] = s;
    __syncthreads();
    for (int d = 128; d >= 1; d >>= 1) {
        if (t < d) red[t] += red[t + d];
        __syncthreads();
    }
    if (t == 0) bsum[blockIdx.x] = red[0];
}

// phase 2: single block, inclusive scan of the block sums (nb <= 256)
__global__ __launch_bounds__(256) void k_scan_sums(int* __restrict__ bsum, int nb) {
    __shared__ int sh[256];
    const int t = threadIdx.x;
    sh[t] = (t < nb) ? bsum[t] : 0;
    __syncthreads();
    for (int d = 1; d < 256; d <<= 1) {
        int v = (t >= d) ? sh[t - d] : 0;
        __syncthreads();
        sh[t] += v;
        __syncthreads();
    }
    if (t < nb) bsum[t] = sh[t];   // inclusive prefix
}

// phase 3: per-block local scan + emit rowptr/fillpos/deg_inv
__global__ __launch_bounds__(256) void k_emit(const int* __restrict__ deg,
                                              const int* __restrict__ bsum_incl,
                                              int* __restrict__ rowptr,
                                              int* __restrict__ fillpos,
                                              float* __restrict__ deg_inv) {
    __shared__ int sh[256];
    const int b = blockIdx.x;
    const int t = threadIdx.x;
    const int i0 = b * SCAN_CHUNK + t * 2;
    const int d0 = (i0 < N)     ? deg[i0]     : 0;
    const int d1 = (i0 + 1 < N) ? deg[i0 + 1] : 0;
    sh[t] = d0 + d1;
    __syncthreads();
    for (int d = 1; d < 256; d <<= 1) {
        int v = (t >= d) ? sh[t - d] : 0;
        __syncthreads();
        sh[t] += v;
        __syncthreads();
    }
    const int blockbase = (b == 0) ? 0 : bsum_incl[b - 1];
    const int base = blockbase + ((t == 0) ? 0 : sh[t - 1]);
    if (i0 < N) {
        rowptr[i0]  = base;
        fillpos[i0] = base;
        deg_inv[i0] = 1.0f / fmaxf((float)d0, 1.0f);
    }
    if (i0 + 1 < N) {
        rowptr[i0 + 1]  = base + d0;
        fillpos[i0 + 1] = base + d0;
        deg_inv[i0 + 1] = 1.0f / fmaxf((float)d1, 1.0f);
    }
    if (b == 0 && t == 0) rowptr[N] = bsum_incl[SCAN_BLOCKS - 1];
}

__global__ void k_fill(const int* __restrict__ src, const int* __restrict__ dst,
                       int* __restrict__ fillpos, int* __restrict__ csr) {
    int i = blockIdx.x * blockDim.x + threadIdx.x;
    if (i < E) {
        int d = dst[i];
        int pos = atomicAdd(&fillpos[d], 1);
        csr[pos] = src[i];
    }
}

// ---------------- layer 1 ----------------
// agg1[n][d] = deg_inv[n] * sum_{s in nbr(n)} x[s][d]   (d < 15)
__global__ __launch_bounds__(256) void k_agg1(const int* __restrict__ rowptr,
                                              const int* __restrict__ csr,
                                              const float* __restrict__ x,
                                              const float* __restrict__ deg_inv,
                                              float* __restrict__ agg1) {
    int g = threadIdx.x >> 4;        // 16 rows per block
    int d = threadIdx.x & 15;
    int n = blockIdx.x * 16 + g;
    if (n >= N || d >= DIN) return;
    int lo = rowptr[n], hi = rowptr[n + 1];
    float acc = 0.f;
    for (int i = lo; i < hi; ++i) {
        int s = csr[i];
        acc += x[s * DIN + d];
    }
    agg1[n * DIN + d] = acc * deg_inv[n];
}

// h1[n][j] = relu(agg1[n]·W1l[:,j] + x[n]·W1r[:,j] + b1[j])
__global__ __launch_bounds__(256) void k_h1(const float* __restrict__ x,
                                            const float* __restrict__ agg1,
                                            const float* __restrict__ W1l,
                                            const float* __restrict__ W1r,
                                            const float* __restrict__ b1,
                                            float* __restrict__ h1) {
    __shared__ float sWl[DIN * DH];
    __shared__ float sWr[DIN * DH];
    __shared__ float sb[DH];
    for (int i = threadIdx.x; i < DIN * DH; i += 256) {
        sWl[i] = W1l[i];
        sWr[i] = W1r[i];
    }
    if (threadIdx.x < DH) sb[threadIdx.x] = b1[threadIdx.x];
    __syncthreads();
    int j = threadIdx.x & 127;
    for (int n = blockIdx.x * 2 + (threadIdx.x >> 7); n < N; n += gridDim.x * 2) {
        const float* ar = &agg1[n * DIN];
        const float* xr = &x[n * DIN];
        float acc = sb[j];
#pragma unroll
        for (int k = 0; k < DIN; ++k)
            acc = fmaf(ar[k], sWl[k * DH + j], fmaf(xr[k], sWr[k * DH + j], acc));
        h1[n * DH + j] = fmaxf(acc, 0.f);
    }
}

// ---------------- layer 2 aggregation (SpMM) ----------------
// agg2[n][d] = deg_inv[n] * sum_{s in nbr(n)} h1[s][d]
__global__ __launch_bounds__(256) void k_agg2(const int* __restrict__ rowptr,
                                              const int* __restrict__ csr,
                                              const float* __restrict__ h1,
                                              const float* __restrict__ deg_inv,
                                              float* __restrict__ agg2) {
    int n = blockIdx.x * 2 + (threadIdx.x >> 7);
    int d = threadIdx.x & 127;
    if (n >= N) return;
    int lo = rowptr[n], hi = rowptr[n + 1];
    float acc = 0.f;
    int i = lo;
    for (; i + 1 < hi; i += 2) {
        int s0 = csr[i], s1 = csr[i + 1];
        acc += h1[s0 * DH + d];
        acc += h1[s1 * DH + d];
    }
    if (i < hi) acc += h1[csr[i] * DH + d];
    agg2[n * DH + d] = acc * deg_inv[n];
}

// ---------------- layer 2 GEMM + layer 3 projection ----------------
// per node: h2 = relu(agg2·W2l + h1·W2r + b2); p = h2·W3l; r = h2·W3r
#define NT 32   // nodes per block
#define KT 16   // k-tile
__global__ __launch_bounds__(256) void k_h2pr(const float* __restrict__ agg2,
                                              const float* __restrict__ h1,
                                              const float* __restrict__ W2l,
                                              const float* __restrict__ W2r,
                                              const float* __restrict__ b2,
                                              const float* __restrict__ W3l,
                                              const float* __restrict__ W3r,
                                              float* __restrict__ p,
                                              float* __restrict__ r) {
    __shared__ float sAT[DH][NT + 4];   // [k][n] transposed, padded
    __shared__ float sHT[DH][NT + 4];
    __shared__ float sWl[KT][DH];
    __shared__ float sWr[KT][DH];
    __shared__ float sW3l[DH], sW3r[DH], sb2[DH];

    const int tid = threadIdx.x;
    const int node0 = blockIdx.x * NT;

    for (int idx = tid; idx < NT * DH; idx += 256) {
        int n = idx >> 7, d = idx & 127;
        sAT[d][n] = agg2[(node0 + n) * DH + d];
        sHT[d][n] = h1[(node0 + n) * DH + d];
    }
    if (tid < DH) {
        sb2[tid]  = b2[tid];
        sW3l[tid] = W3l[tid];
        sW3r[tid] = W3r[tid];
    }

    const int jr = tid & 31;   // column group: cols j0..j0+3
    const int nr = tid >> 5;   // node group: nodes n0..n0+3
    const int j0 = jr * 4;
    const int n0 = nr * 4;

    float acc[4][4] = {{0.f}};   // [node][col]

    for (int kt = 0; kt < DH / KT; ++kt) {
        __syncthreads();
        for (int idx = tid; idx < KT * DH; idx += 256) {
            int kk = idx >> 7, c = idx & 127;
            sWl[kk][c] = W2l[(kt * KT + kk) * DH + c];
            sWr[kk][c] = W2r[(kt * KT + kk) * DH + c];
        }
        __syncthreads();
#pragma unroll
        for (int kk = 0; kk < KT; ++kk) {
            const int k = kt * KT + kk;
            float4 a4 = *(const float4*)&sAT[k][n0];
            float4 h4 = *(const float4*)&sHT[k][n0];
            float4 wl = *(const float4*)&sWl[kk][j0];
            float4 wr = *(const float4*)&sWr[kk][j0];
            const float av[4] = {a4.x, a4.y, a4.z, a4.w};
            const float hv[4] = {h4.x, h4.y, h4.z, h4.w};
            const float wlv[4] = {wl.x, wl.y, wl.z, wl.w};
            const float wrv[4] = {wr.x, wr.y, wr.z, wr.w};
#pragma unroll
            for (int a = 0; a < 4; ++a)
#pragma unroll
                for (int b = 0; b < 4; ++b)
                    acc[a][b] = fmaf(av[a], wlv[b], fmaf(hv[a], wrv[b], acc[a][b]));
        }
    }

    // epilogue: bias + relu + contract with W3l/W3r, reduce over column groups
    float pp[4] = {0.f, 0.f, 0.f, 0.f};
    float rr[4] = {0.f, 0.f, 0.f, 0.f};
#pragma unroll
    for (int a = 0; a < 4; ++a) {
#pragma unroll
        for (int b = 0; b < 4; ++b) {
            float h2v = fmaxf(acc[a][b] + sb2[j0 + b], 0.f);
            pp[a] = fmaf(h2v, sW3l[j0 + b], pp[a]);
            rr[a] = fmaf(h2v, sW3r[j0 + b], rr[a]);
        }
    }
#pragma unroll
    for (int m = 16; m >= 1; m >>= 1) {
#pragma unroll
        for (int a = 0; a < 4; ++a) {
            pp[a] += __shfl_xor(pp[a], m, 64);
            rr[a] += __shfl_xor(rr[a], m, 64);
        }
    }
    if (jr == 0) {
#pragma unroll
        for (int a = 0; a < 4; ++a) {
            p[node0 + n0 + a] = pp[a];
            r[node0 + n0 + a] = rr[a];
        }
    }
}

// ---------------- output ----------------
// out[n] = deg_inv[n] * sum_{s in nbr(n)} p[s] + r[n] + b3
__global__ void k_out(const int* __restrict__ rowptr, const int* __restrict__ csr,
                      const float* __restrict__ p, const float* __restrict__ r,
                      const float* __restrict__ deg_inv, const float* __restrict__ b3,
                      float* __restrict__ out) {
    int n = blockIdx.x * blockDim.x + threadIdx.x;
    if (n >= N) return;
    int lo = rowptr[n], hi = rowptr[n + 1];
    float acc = 0.f;
    for (int i = lo; i < hi; ++i) acc += p[csr[i]];
    out[n] = acc * deg_inv[n] + r[n] + b3[0];
}

// ---------------- host ----------------
extern "C" void kernel_launch(void* const* d_in, const int* in_sizes, int n_in,
                              void* d_out, int out_size, void* d_ws, size_t ws_size,
                              hipStream_t stream) {
    const float* x    = (const float*)d_in[0];
    const int*   eidx = (const int*)d_in[1];   // [2,E] flat: row0=src, row1=dst
    const float* W1l  = (const float*)d_in[2];
    const float* W1r  = (const float*)d_in[3];
    const float* b1   = (const float*)d_in[4];
    const float* W2l  = (const float*)d_in[5];
    const float* W2r  = (const float*)d_in[6];
    const float* b2   = (const float*)d_in[7];
    const float* W3l  = (const float*)d_in[8];
    const float* W3r  = (const float*)d_in[9];
    const float* b3   = (const float*)d_in[10];
    float* out = (float*)d_out;

    const int* srcs = eidx;
    const int* dsts = eidx + E;

    // workspace carve-up (256B aligned)
    size_t off = 0;
    auto alloc = [&](size_t bytes) {
        size_t o = off;
        off = (off + bytes + 255) & ~(size_t)255;
        return o;
    };
    char* w = (char*)d_ws;
    int*   deg_i   = (int*)(w + alloc((size_t)N * 4));
    int*   rowptr  = (int*)(w + alloc((size_t)(N + 1) * 4));
    int*   fillpos = (int*)(w + alloc((size_t)N * 4));
    int*   csr     = (int*)(w + alloc((size_t)E * 4));
    float* deg_inv = (float*)(w + alloc((size_t)N * 4));
    float* agg1    = (float*)(w + alloc((size_t)N * DIN * 4));
    float* h1      = (float*)(w + alloc((size_t)N * DH * 4));
    float* agg2    = (float*)(w + alloc((size_t)N * DH * 4));
    float* pbuf    = (float*)(w + alloc((size_t)N * 4));
    float* rbuf    = (float*)(w + alloc((size_t)N * 4));
    int*   bsum    = (int*)(w + alloc((size_t)SCAN_BLOCKS * 4));
    (void)ws_size;

    // 1. CSR build (parallel 3-phase scan)
    k_zero_int<<<(N + 255) / 256, 256, 0, stream>>>(deg_i, N);
    k_degree<<<(E + 255) / 256, 256, 0, stream>>>(dsts, deg_i);
    k_block_sums<<<SCAN_BLOCKS, 256, 0, stream>>>(deg_i, bsum);
    k_scan_sums<<<1, 256, 0, stream>>>(bsum, SCAN_BLOCKS);
    k_emit<<<SCAN_BLOCKS, 256, 0, stream>>>(deg_i, bsum, rowptr, fillpos, deg_inv);
    k_fill<<<(E + 255) / 256, 256, 0, stream>>>(srcs, dsts, fillpos, csr);

    // 2. layer 1
    k_agg1<<<(N + 15) / 16, 256, 0, stream>>>(rowptr, csr, x, deg_inv, agg1);
    k_h1<<<1024, 256, 0, stream>>>(x, agg1, W1l, W1r, b1, h1);

    // 3. layer 2 aggregation
    k_agg2<<<(N + 1) / 2, 256, 0, stream>>>(rowptr, csr, h1, deg_inv, agg2);

    // 4. layer 2 GEMM + layer-3 projection (p = h2·W3l, r = h2·W3r)
    k_h2pr<<<(N + NT - 1) / NT, 256, 0, stream>>>(agg2, h1, W2l, W2r, b2, W3l, W3r,
                                                  pbuf, rbuf);

    // 5. output: scalar aggregation of p
    k_out<<<(N + 255) / 256, 256, 0, stream>>>(rowptr, csr, pbuf, rbuf, deg_inv, b3, out);
}

// Round 3
// 532.677 us; speedup vs baseline: 1.7452x; 1.2458x over previous
//
#include <hip/hip_runtime.h>
#include <hip/hip_bf16.h>

constexpr int N = 100000;      // nodes
constexpr int E = 1600000;     // edges
constexpr int DIN = 15;
constexpr int DH  = 128;

constexpr int SCAN_CHUNK  = 512;                                  // elems per block
constexpr int SCAN_BLOCKS = (N + SCAN_CHUNK - 1) / SCAN_CHUNK;    // 196

__device__ __forceinline__ unsigned short f2bf_rne(float f) {
    unsigned u = __float_as_uint(f);
    u += 0x7fffu + ((u >> 16) & 1u);
    return (unsigned short)(u >> 16);
}

// ---------------- utility ----------------
__global__ void k_zero_int(int* __restrict__ p, int n) {
    int i = blockIdx.x * blockDim.x + threadIdx.x;
    if (i < n) p[i] = 0;
}

// ---------------- CSR build ----------------
__global__ void k_degree(const int* __restrict__ dst, int* __restrict__ deg) {
    int i = blockIdx.x * blockDim.x + threadIdx.x;
    if (i < E) atomicAdd(&deg[dst[i]], 1);
}

// phase 1: per-block sum of a 512-element chunk of deg
__global__ __launch_bounds__(256) void k_block_sums(const int* __restrict__ deg,
                                                    int* __restrict__ bsum) {
    __shared__ int red[256];
    const int t = threadIdx.x;
    const int i0 = blockIdx.x * SCAN_CHUNK + t * 2;
    int s = 0;
    if (i0 < N)     s += deg[i0];
    if (i0 + 1 < N) s += deg[i0 + 1];
    red[t] = s;
    __syncthreads();
    for (int d = 128; d >= 1; d >>= 1) {
        if (t < d) red[t] += red[t + d];
        __syncthreads();
    }
    if (t == 0) bsum[blockIdx.x] = red[0];
}

// phase 2: single block, inclusive scan of the block sums (nb <= 256)
__global__ __launch_bounds__(256) void k_scan_sums(int* __restrict__ bsum, int nb) {
    __shared__ int sh[256];
    const int t = threadIdx.x;
    sh[t] = (t < nb) ? bsum[t] : 0;
    __syncthreads();
    for (int d = 1; d < 256; d <<= 1) {
        int v = (t >= d) ? sh[t - d] : 0;
        __syncthreads();
        sh[t] += v;
        __syncthreads();
    }
    if (t < nb) bsum[t] = sh[t];   // inclusive prefix
}

// phase 3: per-block local scan + emit rowptr/fillpos/deg_inv
__global__ __launch_bounds__(256) void k_emit(const int* __restrict__ deg,
                                              const int* __restrict__ bsum_incl,
                                              int* __restrict__ rowptr,
                                              int* __restrict__ fillpos,
                                              float* __restrict__ deg_inv) {
    __shared__ int sh[256];
    const int b = blockIdx.x;
    const int t = threadIdx.x;
    const int i0 = b * SCAN_CHUNK + t * 2;
    const int d0 = (i0 < N)     ? deg[i0]     : 0;
    const int d1 = (i0 + 1 < N) ? deg[i0 + 1] : 0;
    sh[t] = d0 + d1;
    __syncthreads();
    for (int d = 1; d < 256; d <<= 1) {
        int v = (t >= d) ? sh[t - d] : 0;
        __syncthreads();
        sh[t] += v;
        __syncthreads();
    }
    const int blockbase = (b == 0) ? 0 : bsum_incl[b - 1];
    const int base = blockbase + ((t == 0) ? 0 : sh[t - 1]);
    if (i0 < N) {
        rowptr[i0]  = base;
        fillpos[i0] = base;
        deg_inv[i0] = 1.0f / fmaxf((float)d0, 1.0f);
    }
    if (i0 + 1 < N) {
        rowptr[i0 + 1]  = base + d0;
        fillpos[i0 + 1] = base + d0;
        deg_inv[i0 + 1] = 1.0f / fmaxf((float)d1, 1.0f);
    }
    if (b == 0 && t == 0) rowptr[N] = bsum_incl[SCAN_BLOCKS - 1];
}

__global__ void k_fill(const int* __restrict__ src, const int* __restrict__ dst,
                       int* __restrict__ fillpos, int* __restrict__ csr) {
    int i = blockIdx.x * blockDim.x + threadIdx.x;
    if (i < E) {
        int d = dst[i];
        int pos = atomicAdd(&fillpos[d], 1);
        csr[pos] = src[i];
    }
}

// ---------------- layer 1 ----------------
// agg1[n][d] = deg_inv[n] * sum_{s in nbr(n)} x[s][d]   (d < 15)
__global__ __launch_bounds__(256) void k_agg1(const int* __restrict__ rowptr,
                                              const int* __restrict__ csr,
                                              const float* __restrict__ x,
                                              const float* __restrict__ deg_inv,
                                              float* __restrict__ agg1) {
    int g = threadIdx.x >> 4;        // 16 rows per block
    int d = threadIdx.x & 15;
    int n = blockIdx.x * 16 + g;
    if (n >= N || d >= DIN) return;
    int lo = rowptr[n], hi = rowptr[n + 1];
    float a0 = 0.f, a1 = 0.f, a2 = 0.f, a3 = 0.f;
    int i = lo;
    for (; i + 3 < hi; i += 4) {
        int s0 = csr[i], s1 = csr[i + 1], s2 = csr[i + 2], s3 = csr[i + 3];
        a0 += x[s0 * DIN + d];
        a1 += x[s1 * DIN + d];
        a2 += x[s2 * DIN + d];
        a3 += x[s3 * DIN + d];
    }
    for (; i < hi; ++i) a0 += x[csr[i] * DIN + d];
    agg1[n * DIN + d] = ((a0 + a1) + (a2 + a3)) * deg_inv[n];
}

// h1[n][j] = relu(agg1[n]·W1l[:,j] + x[n]·W1r[:,j] + b1[j]); also emit bf16 copy
__global__ __launch_bounds__(256) void k_h1(const float* __restrict__ x,
                                            const float* __restrict__ agg1,
                                            const float* __restrict__ W1l,
                                            const float* __restrict__ W1r,
                                            const float* __restrict__ b1,
                                            float* __restrict__ h1,
                                            unsigned short* __restrict__ h1b) {
    __shared__ float sWl[DIN * DH];
    __shared__ float sWr[DIN * DH];
    __shared__ float sb[DH];
    for (int i = threadIdx.x; i < DIN * DH; i += 256) {
        sWl[i] = W1l[i];
        sWr[i] = W1r[i];
    }
    if (threadIdx.x < DH) sb[threadIdx.x] = b1[threadIdx.x];
    __syncthreads();
    int j = threadIdx.x & 127;
    for (int n = blockIdx.x * 2 + (threadIdx.x >> 7); n < N; n += gridDim.x * 2) {
        const float* ar = &agg1[n * DIN];
        const float* xr = &x[n * DIN];
        float acc = sb[j];
#pragma unroll
        for (int k = 0; k < DIN; ++k)
            acc = fmaf(ar[k], sWl[k * DH + j], fmaf(xr[k], sWr[k * DH + j], acc));
        float v = fmaxf(acc, 0.f);
        h1[n * DH + j]  = v;
        h1b[n * DH + j] = f2bf_rne(v);
    }
}

// ---------------- layer 2 aggregation (SpMM, bf16 gather) ----------------
// agg2[n][d] = deg_inv[n] * sum_{s in nbr(n)} h1[s][d]
// one wave per node; lane covers d = 2*lane, 2*lane+1 via one uint (bf16x2)
__global__ __launch_bounds__(256) void k_agg2(const int* __restrict__ rowptr,
                                              const int* __restrict__ csr,
                                              const unsigned int* __restrict__ h1b,
                                              const float* __restrict__ deg_inv,
                                              float* __restrict__ agg2) {
    const int lane = threadIdx.x & 63;
    const int n = blockIdx.x * 4 + (threadIdx.x >> 6);
    if (n >= N) return;
    const int lo = rowptr[n], hi = rowptr[n + 1];
    float a0x = 0.f, a0y = 0.f, a1x = 0.f, a1y = 0.f;
    float a2x = 0.f, a2y = 0.f, a3x = 0.f, a3y = 0.f;
    int i = lo;
    for (; i + 3 < hi; i += 4) {
        int s0 = csr[i], s1 = csr[i + 1], s2 = csr[i + 2], s3 = csr[i + 3];
        unsigned u0 = h1b[s0 * 64 + lane];
        unsigned u1 = h1b[s1 * 64 + lane];
        unsigned u2 = h1b[s2 * 64 + lane];
        unsigned u3 = h1b[s3 * 64 + lane];
        a0x += __uint_as_float(u0 << 16); a0y += __uint_as_float(u0 & 0xffff0000u);
        a1x += __uint_as_float(u1 << 16); a1y += __uint_as_float(u1 & 0xffff0000u);
        a2x += __uint_as_float(u2 << 16); a2y += __uint_as_float(u2 & 0xffff0000u);
        a3x += __uint_as_float(u3 << 16); a3y += __uint_as_float(u3 & 0xffff0000u);
    }
    for (; i < hi; ++i) {
        unsigned u = h1b[csr[i] * 64 + lane];
        a0x += __uint_as_float(u << 16); a0y += __uint_as_float(u & 0xffff0000u);
    }
    const float di = deg_inv[n];
    float2 r;
    r.x = ((a0x + a1x) + (a2x + a3x)) * di;
    r.y = ((a0y + a1y) + (a2y + a3y)) * di;
    ((float2*)agg2)[n * 64 + lane] = r;
}

// ---------------- layer 2 GEMM + layer 3 projection ----------------
// per node: h2 = relu(agg2·W2l + h1·W2r + b2); p = h2·W3l; r = h2·W3r
#define NT 32   // nodes per block
#define KT 16   // k-tile
__global__ __launch_bounds__(256) void k_h2pr(const float* __restrict__ agg2,
                                              const float* __restrict__ h1,
                                              const float* __restrict__ W2l,
                                              const float* __restrict__ W2r,
                                              const float* __restrict__ b2,
                                              const float* __restrict__ W3l,
                                              const float* __restrict__ W3r,
                                              float* __restrict__ p,
                                              float* __restrict__ r) {
    __shared__ float sAT[DH][NT + 4];   // [k][n] transposed, padded
    __shared__ float sHT[DH][NT + 4];
    __shared__ float sWl[KT][DH];
    __shared__ float sWr[KT][DH];
    __shared__ float sW3l[DH], sW3r[DH], sb2[DH];

    const int tid = threadIdx.x;
    const int node0 = blockIdx.x * NT;

    for (int idx = tid; idx < NT * DH; idx += 256) {
        int n = idx >> 7, d = idx & 127;
        sAT[d][n] = agg2[(node0 + n) * DH + d];
        sHT[d][n] = h1[(node0 + n) * DH + d];
    }
    if (tid < DH) {
        sb2[tid]  = b2[tid];
        sW3l[tid] = W3l[tid];
        sW3r[tid] = W3r[tid];
    }

    const int jr = tid & 31;   // column group: cols j0..j0+3
    const int nr = tid >> 5;   // node group: nodes n0..n0+3
    const int j0 = jr * 4;
    const int n0 = nr * 4;

    float acc[4][4] = {{0.f}};   // [node][col]

    for (int kt = 0; kt < DH / KT; ++kt) {
        __syncthreads();
        for (int idx = tid; idx < KT * DH; idx += 256) {
            int kk = idx >> 7, c = idx & 127;
            sWl[kk][c] = W2l[(kt * KT + kk) * DH + c];
            sWr[kk][c] = W2r[(kt * KT + kk) * DH + c];
        }
        __syncthreads();
#pragma unroll
        for (int kk = 0; kk < KT; ++kk) {
            const int k = kt * KT + kk;
            float4 a4 = *(const float4*)&sAT[k][n0];
            float4 h4 = *(const float4*)&sHT[k][n0];
            float4 wl = *(const float4*)&sWl[kk][j0];
            float4 wr = *(const float4*)&sWr[kk][j0];
            const float av[4] = {a4.x, a4.y, a4.z, a4.w};
            const float hv[4] = {h4.x, h4.y, h4.z, h4.w};
            const float wlv[4] = {wl.x, wl.y, wl.z, wl.w};
            const float wrv[4] = {wr.x, wr.y, wr.z, wr.w};
#pragma unroll
            for (int a = 0; a < 4; ++a)
#pragma unroll
                for (int b = 0; b < 4; ++b)
                    acc[a][b] = fmaf(av[a], wlv[b], fmaf(hv[a], wrv[b], acc[a][b]));
        }
    }

    // epilogue: bias + relu + contract with W3l/W3r, reduce over column groups
    float pp[4] = {0.f, 0.f, 0.f, 0.f};
    float rr[4] = {0.f, 0.f, 0.f, 0.f};
#pragma unroll
    for (int a = 0; a < 4; ++a) {
#pragma unroll
        for (int b = 0; b < 4; ++b) {
            float h2v = fmaxf(acc[a][b] + sb2[j0 + b], 0.f);
            pp[a] = fmaf(h2v, sW3l[j0 + b], pp[a]);
            rr[a] = fmaf(h2v, sW3r[j0 + b], rr[a]);
        }
    }
#pragma unroll
    for (int m = 16; m >= 1; m >>= 1) {
#pragma unroll
        for (int a = 0; a < 4; ++a) {
            pp[a] += __shfl_xor(pp[a], m, 64);
            rr[a] += __shfl_xor(rr[a], m, 64);
        }
    }
    if (jr == 0) {
#pragma unroll
        for (int a = 0; a < 4; ++a) {
            p[node0 + n0 + a] = pp[a];
            r[node0 + n0 + a] = rr[a];
        }
    }
}

// ---------------- output ----------------
// out[n] = deg_inv[n] * sum_{s in nbr(n)} p[s] + r[n] + b3
__global__ void k_out(const int* __restrict__ rowptr, const int* __restrict__ csr,
                      const float* __restrict__ p, const float* __restrict__ r,
                      const float* __restrict__ deg_inv, const float* __restrict__ b3,
                      float* __restrict__ out) {
    int n = blockIdx.x * blockDim.x + threadIdx.x;
    if (n >= N) return;
    int lo = rowptr[n], hi = rowptr[n + 1];
    float a0 = 0.f, a1 = 0.f, a2 = 0.f, a3 = 0.f;
    int i = lo;
    for (; i + 3 < hi; i += 4) {
        a0 += p[csr[i]];
        a1 += p[csr[i + 1]];
        a2 += p[csr[i + 2]];
        a3 += p[csr[i + 3]];
    }
    for (; i < hi; ++i) a0 += p[csr[i]];
    out[n] = ((a0 + a1) + (a2 + a3)) * deg_inv[n] + r[n] + b3[0];
}

// ---------------- host ----------------
extern "C" void kernel_launch(void* const* d_in, const int* in_sizes, int n_in,
                              void* d_out, int out_size, void* d_ws, size_t ws_size,
                              hipStream_t stream) {
    const float* x    = (const float*)d_in[0];
    const int*   eidx = (const int*)d_in[1];   // [2,E] flat: row0=src, row1=dst
    const float* W1l  = (const float*)d_in[2];
    const float* W1r  = (const float*)d_in[3];
    const float* b1   = (const float*)d_in[4];
    const float* W2l  = (const float*)d_in[5];
    const float* W2r  = (const float*)d_in[6];
    const float* b2   = (const float*)d_in[7];
    const float* W3l  = (const float*)d_in[8];
    const float* W3r  = (const float*)d_in[9];
    const float* b3   = (const float*)d_in[10];
    float* out = (float*)d_out;

    const int* srcs = eidx;
    const int* dsts = eidx + E;

    // workspace carve-up (256B aligned)
    size_t off = 0;
    auto alloc = [&](size_t bytes) {
        size_t o = off;
        off = (off + bytes + 255) & ~(size_t)255;
        return o;
    };
    char* w = (char*)d_ws;
    int*   deg_i   = (int*)(w + alloc((size_t)N * 4));
    int*   rowptr  = (int*)(w + alloc((size_t)(N + 1) * 4));
    int*   fillpos = (int*)(w + alloc((size_t)N * 4));
    int*   csr     = (int*)(w + alloc((size_t)E * 4));
    float* deg_inv = (float*)(w + alloc((size_t)N * 4));
    float* agg1    = (float*)(w + alloc((size_t)N * DIN * 4));
    float* h1      = (float*)(w + alloc((size_t)N * DH * 4));
    unsigned short* h1b = (unsigned short*)(w + alloc((size_t)N * DH * 2));
    float* agg2    = (float*)(w + alloc((size_t)N * DH * 4));
    float* pbuf    = (float*)(w + alloc((size_t)N * 4));
    float* rbuf    = (float*)(w + alloc((size_t)N * 4));
    int*   bsum    = (int*)(w + alloc((size_t)SCAN_BLOCKS * 4));
    (void)ws_size;

    // 1. CSR build (parallel 3-phase scan)
    k_zero_int<<<(N + 255) / 256, 256, 0, stream>>>(deg_i, N);
    k_degree<<<(E + 255) / 256, 256, 0, stream>>>(dsts, deg_i);
    k_block_sums<<<SCAN_BLOCKS, 256, 0, stream>>>(deg_i, bsum);
    k_scan_sums<<<1, 256, 0, stream>>>(bsum, SCAN_BLOCKS);
    k_emit<<<SCAN_BLOCKS, 256, 0, stream>>>(deg_i, bsum, rowptr, fillpos, deg_inv);
    k_fill<<<(E + 255) / 256, 256, 0, stream>>>(srcs, dsts, fillpos, csr);

    // 2. layer 1
    k_agg1<<<(N + 15) / 16, 256, 0, stream>>>(rowptr, csr, x, deg_inv, agg1);
    k_h1<<<1024, 256, 0, stream>>>(x, agg1, W1l, W1r, b1, h1, h1b);

    // 3. layer 2 aggregation (bf16 gather)
    k_agg2<<<(N + 3) / 4, 256, 0, stream>>>(rowptr, csr, (const unsigned int*)h1b,
                                            deg_inv, agg2);

    // 4. layer 2 GEMM + layer-3 projection (p = h2·W3l, r = h2·W3r)
    k_h2pr<<<(N + NT - 1) / NT, 256, 0, stream>>>(agg2, h1, W2l, W2r, b2, W3l, W3r,
                                                  pbuf, rbuf);

    // 5. output: scalar aggregation of p
    k_out<<<(N + 255) / 256, 256, 0, stream>>>(rowptr, csr, pbuf, rbuf, deg_inv, b3, out);
}

// Round 4
// 421.770 us; speedup vs baseline: 2.2041x; 1.2630x over previous
//
#include <hip/hip_runtime.h>
#include <hip/hip_bf16.h>

constexpr int N = 100000;      // nodes
constexpr int E = 1600000;     // edges
constexpr int DIN = 15;
constexpr int DH  = 128;
constexpr int K2  = 256;       // layer-2 GEMM K = DH (agg2) + DH (h1)

constexpr int SCAN_CHUNK  = 512;                                  // elems per block
constexpr int SCAN_BLOCKS = (N + SCAN_CHUNK - 1) / SCAN_CHUNK;    // 196

typedef short short8 __attribute__((ext_vector_type(8)));
typedef float f32x4  __attribute__((ext_vector_type(4)));

__device__ __forceinline__ unsigned short f2bf_rne(float f) {
    unsigned u = __float_as_uint(f);
    u += 0x7fffu + ((u >> 16) & 1u);
    return (unsigned short)(u >> 16);
}
__device__ __forceinline__ float bf2f(unsigned short h) {
    return __uint_as_float(((unsigned)h) << 16);
}

// ---------------- utility ----------------
__global__ void k_zero_int(int* __restrict__ p, int n) {
    int i = blockIdx.x * blockDim.x + threadIdx.x;
    if (i < n) p[i] = 0;
}

// ---------------- CSR build ----------------
__global__ void k_degree(const int* __restrict__ dst, int* __restrict__ deg) {
    int i = blockIdx.x * blockDim.x + threadIdx.x;
    if (i < E) atomicAdd(&deg[dst[i]], 1);
}

__global__ __launch_bounds__(256) void k_block_sums(const int* __restrict__ deg,
                                                    int* __restrict__ bsum) {
    __shared__ int red[256];
    const int t = threadIdx.x;
    const int i0 = blockIdx.x * SCAN_CHUNK + t * 2;
    int s = 0;
    if (i0 < N)     s += deg[i0];
    if (i0 + 1 < N) s += deg[i0 + 1];
    red[t] = s;
    __syncthreads();
    for (int d = 128; d >= 1; d >>= 1) {
        if (t < d) red[t] += red[t + d];
        __syncthreads();
    }
    if (t == 0) bsum[blockIdx.x] = red[0];
}

__global__ __launch_bounds__(256) void k_scan_sums(int* __restrict__ bsum, int nb) {
    __shared__ int sh[256];
    const int t = threadIdx.x;
    sh[t] = (t < nb) ? bsum[t] : 0;
    __syncthreads();
    for (int d = 1; d < 256; d <<= 1) {
        int v = (t >= d) ? sh[t - d] : 0;
        __syncthreads();
        sh[t] += v;
        __syncthreads();
    }
    if (t < nb) bsum[t] = sh[t];   // inclusive prefix
}

__global__ __launch_bounds__(256) void k_emit(const int* __restrict__ deg,
                                              const int* __restrict__ bsum_incl,
                                              int* __restrict__ rowptr,
                                              int* __restrict__ fillpos,
                                              float* __restrict__ deg_inv) {
    __shared__ int sh[256];
    const int b = blockIdx.x;
    const int t = threadIdx.x;
    const int i0 = b * SCAN_CHUNK + t * 2;
    const int d0 = (i0 < N)     ? deg[i0]     : 0;
    const int d1 = (i0 + 1 < N) ? deg[i0 + 1] : 0;
    sh[t] = d0 + d1;
    __syncthreads();
    for (int d = 1; d < 256; d <<= 1) {
        int v = (t >= d) ? sh[t - d] : 0;
        __syncthreads();
        sh[t] += v;
        __syncthreads();
    }
    const int blockbase = (b == 0) ? 0 : bsum_incl[b - 1];
    const int base = blockbase + ((t == 0) ? 0 : sh[t - 1]);
    if (i0 < N) {
        rowptr[i0]  = base;
        fillpos[i0] = base;
        deg_inv[i0] = 1.0f / fmaxf((float)d0, 1.0f);
    }
    if (i0 + 1 < N) {
        rowptr[i0 + 1]  = base + d0;
        fillpos[i0 + 1] = base + d0;
        deg_inv[i0 + 1] = 1.0f / fmaxf((float)d1, 1.0f);
    }
    if (b == 0 && t == 0) rowptr[N] = bsum_incl[SCAN_BLOCKS - 1];
}

__global__ void k_fill(const int* __restrict__ src, const int* __restrict__ dst,
                       int* __restrict__ fillpos, int* __restrict__ csr) {
    int i = blockIdx.x * blockDim.x + threadIdx.x;
    if (i < E) {
        int d = dst[i];
        int pos = atomicAdd(&fillpos[d], 1);
        csr[pos] = src[i];
    }
}

// ---------------- layer 1 ----------------
__global__ __launch_bounds__(256) void k_agg1(const int* __restrict__ rowptr,
                                              const int* __restrict__ csr,
                                              const float* __restrict__ x,
                                              const float* __restrict__ deg_inv,
                                              float* __restrict__ agg1) {
    int g = threadIdx.x >> 4;        // 16 rows per block
    int d = threadIdx.x & 15;
    int n = blockIdx.x * 16 + g;
    if (n >= N || d >= DIN) return;
    int lo = rowptr[n], hi = rowptr[n + 1];
    float a0 = 0.f, a1 = 0.f, a2 = 0.f, a3 = 0.f;
    int i = lo;
    for (; i + 3 < hi; i += 4) {
        int s0 = csr[i], s1 = csr[i + 1], s2 = csr[i + 2], s3 = csr[i + 3];
        a0 += x[s0 * DIN + d];
        a1 += x[s1 * DIN + d];
        a2 += x[s2 * DIN + d];
        a3 += x[s3 * DIN + d];
    }
    for (; i < hi; ++i) a0 += x[csr[i] * DIN + d];
    agg1[n * DIN + d] = ((a0 + a1) + (a2 + a3)) * deg_inv[n];
}

__global__ __launch_bounds__(256) void k_h1(const float* __restrict__ x,
                                            const float* __restrict__ agg1,
                                            const float* __restrict__ W1l,
                                            const float* __restrict__ W1r,
                                            const float* __restrict__ b1,
                                            float* __restrict__ h1,
                                            unsigned short* __restrict__ h1b) {
    __shared__ float sWl[DIN * DH];
    __shared__ float sWr[DIN * DH];
    __shared__ float sb[DH];
    for (int i = threadIdx.x; i < DIN * DH; i += 256) {
        sWl[i] = W1l[i];
        sWr[i] = W1r[i];
    }
    if (threadIdx.x < DH) sb[threadIdx.x] = b1[threadIdx.x];
    __syncthreads();
    int j = threadIdx.x & 127;
    for (int n = blockIdx.x * 2 + (threadIdx.x >> 7); n < N; n += gridDim.x * 2) {
        const float* ar = &agg1[n * DIN];
        const float* xr = &x[n * DIN];
        float acc = sb[j];
#pragma unroll
        for (int k = 0; k < DIN; ++k)
            acc = fmaf(ar[k], sWl[k * DH + j], fmaf(xr[k], sWr[k * DH + j], acc));
        float v = fmaxf(acc, 0.f);
        h1[n * DH + j]  = v;
        h1b[n * DH + j] = f2bf_rne(v);
    }
}

// ---------------- layer 2 aggregation (SpMM, bf16 gather) ----------------
__global__ __launch_bounds__(256) void k_agg2(const int* __restrict__ rowptr,
                                              const int* __restrict__ csr,
                                              const unsigned int* __restrict__ h1b,
                                              const float* __restrict__ deg_inv,
                                              float* __restrict__ agg2) {
    const int lane = threadIdx.x & 63;
    const int n = blockIdx.x * 4 + (threadIdx.x >> 6);
    if (n >= N) return;
    const int lo = rowptr[n], hi = rowptr[n + 1];
    float a0x = 0.f, a0y = 0.f, a1x = 0.f, a1y = 0.f;
    float a2x = 0.f, a2y = 0.f, a3x = 0.f, a3y = 0.f;
    int i = lo;
    for (; i + 3 < hi; i += 4) {
        int s0 = csr[i], s1 = csr[i + 1], s2 = csr[i + 2], s3 = csr[i + 3];
        unsigned u0 = h1b[s0 * 64 + lane];
        unsigned u1 = h1b[s1 * 64 + lane];
        unsigned u2 = h1b[s2 * 64 + lane];
        unsigned u3 = h1b[s3 * 64 + lane];
        a0x += __uint_as_float(u0 << 16); a0y += __uint_as_float(u0 & 0xffff0000u);
        a1x += __uint_as_float(u1 << 16); a1y += __uint_as_float(u1 & 0xffff0000u);
        a2x += __uint_as_float(u2 << 16); a2y += __uint_as_float(u2 & 0xffff0000u);
        a3x += __uint_as_float(u3 << 16); a3y += __uint_as_float(u3 & 0xffff0000u);
    }
    for (; i < hi; ++i) {
        unsigned u = h1b[csr[i] * 64 + lane];
        a0x += __uint_as_float(u << 16); a0y += __uint_as_float(u & 0xffff0000u);
    }
    const float di = deg_inv[n];
    float2 r;
    r.x = ((a0x + a1x) + (a2x + a3x)) * di;
    r.y = ((a0y + a1y) + (a2y + a3y)) * di;
    ((float2*)agg2)[n * 64 + lane] = r;
}

// ---------------- W2 prep: transpose + hi/lo bf16 split ----------------
// Wt[col][k]: k<128 -> W2l[k][col], k>=128 -> W2r[k-128][col]
__global__ __launch_bounds__(256) void k_prepw(const float* __restrict__ W2l,
                                               const float* __restrict__ W2r,
                                               unsigned short* __restrict__ Wthi,
                                               unsigned short* __restrict__ Wtlo) {
    int id = blockIdx.x * 256 + threadIdx.x;       // 128 cols * 256 k
    if (id >= DH * K2) return;
    int col = id & 127;
    int k   = id >> 7;
    float wv = (k < DH) ? W2l[k * DH + col] : W2r[(k - DH) * DH + col];
    unsigned short hi = f2bf_rne(wv);
    unsigned short lo = f2bf_rne(wv - bf2f(hi));
    Wthi[col * K2 + k] = hi;
    Wtlo[col * K2 + k] = lo;
}

// ---------------- layer 2 GEMM + layer 3 projection (MFMA, split-bf16) ------
// Per block: 32 nodes, K=256 (agg2||h1), 128 output cols.
// h2 = relu(A@Wt + b2); p = h2.W3l; r = h2.W3r.
// Split precision: A = Ahi + Alo, W = Whi + Wlo; C ~= Ahi Whi + Alo Whi + Ahi Wlo.
__global__ __launch_bounds__(256) void k_h2pr(const float* __restrict__ agg2,
                                              const float* __restrict__ h1,
                                              const unsigned short* __restrict__ Wthi,
                                              const unsigned short* __restrict__ Wtlo,
                                              const float* __restrict__ b2,
                                              const float* __restrict__ W3l,
                                              const float* __restrict__ W3r,
                                              float* __restrict__ p,
                                              float* __restrict__ r) {
    // A staged as bf16 hi/lo, layout: chunk c=k/8 in [0,32), node n in [0,32)
    // idx(c,n) = c*32 + (n ^ (c&7)); entry = 8 contiguous bf16 (16B)
    __shared__ __align__(16) unsigned short sAhi[32 * 32 * 8];   // 16 KB
    __shared__ __align__(16) unsigned short sAlo[32 * 32 * 8];   // 16 KB
    __shared__ float sb2[DH], sW3l[DH], sW3r[DH];
    __shared__ float sPP[4 * 32], sPR[4 * 32];

    const int tid   = threadIdx.x;
    const int node0 = blockIdx.x * 32;

    if (tid < DH) {
        sb2[tid]  = b2[tid];
        sW3l[tid] = W3l[tid];
        sW3r[tid] = W3r[tid];
    }

    // ---- stage A (32 nodes x 256 k) as hi/lo bf16 ----
    {
        const int c = tid & 31;            // k-chunk (8 k's)
        const int nb = tid >> 5;           // node base (0..7), +8 per iter
#pragma unroll
        for (int it = 0; it < 4; ++it) {
            const int n = nb + it * 8;
            const int row = node0 + n;
            const float* src = (c < 16) ? &agg2[row * DH + c * 8]
                                        : &h1[row * DH + (c - 16) * 8];
            float4 v0 = *(const float4*)src;
            float4 v1 = *(const float4*)(src + 4);
            float v[8] = {v0.x, v0.y, v0.z, v0.w, v1.x, v1.y, v1.z, v1.w};
            unsigned hs[8], ls[8];
#pragma unroll
            for (int j = 0; j < 8; ++j) {
                unsigned short h = f2bf_rne(v[j]);
                unsigned short l2 = f2bf_rne(v[j] - bf2f(h));
                hs[j] = h; ls[j] = l2;
            }
            const int idx = (c * 32 + (n ^ (c & 7))) * 8;
            uint4 uh = {hs[0] | (hs[1] << 16), hs[2] | (hs[3] << 16),
                        hs[4] | (hs[5] << 16), hs[6] | (hs[7] << 16)};
            uint4 ul = {ls[0] | (ls[1] << 16), ls[2] | (ls[3] << 16),
                        ls[4] | (ls[5] << 16), ls[6] | (ls[7] << 16)};
            *(uint4*)&sAhi[idx] = uh;
            *(uint4*)&sAlo[idx] = ul;
        }
    }
    __syncthreads();

    // ---- MFMA main loop ----
    const int w    = tid >> 6;     // wave 0..3 -> cols [32w, 32w+32)
    const int lane = tid & 63;
    const int cg   = lane & 15;    // col-in-tile / row-in-tile selector
    const int lg   = lane >> 4;    // k-subchunk / row-subgroup

    f32x4 acc[2][2];               // [row-tile r][col-tile ci]
#pragma unroll
    for (int a = 0; a < 2; ++a)
#pragma unroll
        for (int b = 0; b < 2; ++b)
            acc[a][b] = (f32x4){0.f, 0.f, 0.f, 0.f};

    // B pointers: Wt[col][k], col = w*32 + ci*16 + cg, frag k = s*32 + lg*8
    const unsigned short* bhp0 = &Wthi[(w * 32 + 0 * 16 + cg) * K2 + lg * 8];
    const unsigned short* bhp1 = &Wthi[(w * 32 + 1 * 16 + cg) * K2 + lg * 8];
    const unsigned short* blp0 = &Wtlo[(w * 32 + 0 * 16 + cg) * K2 + lg * 8];
    const unsigned short* blp1 = &Wtlo[(w * 32 + 1 * 16 + cg) * K2 + lg * 8];

#pragma unroll
    for (int s = 0; s < 8; ++s) {
        // A fragments: row-tile r, rows r*16+cg, k = s*32 + lg*8
        short8 ahi[2], alo[2];
#pragma unroll
        for (int rt = 0; rt < 2; ++rt) {
            const int c = s * 4 + lg;
            const int n = rt * 16 + cg;
            const int idx = (c * 32 + (n ^ (c & 7))) * 8;
            ahi[rt] = *(const short8*)&sAhi[idx];
            alo[rt] = *(const short8*)&sAlo[idx];
        }
        short8 bhi[2], blo[2];
        bhi[0] = *(const short8*)(bhp0 + s * 32);
        bhi[1] = *(const short8*)(bhp1 + s * 32);
        blo[0] = *(const short8*)(blp0 + s * 32);
        blo[1] = *(const short8*)(blp1 + s * 32);
#pragma unroll
        for (int rt = 0; rt < 2; ++rt)
#pragma unroll
            for (int ci = 0; ci < 2; ++ci) {
                acc[rt][ci] = __builtin_amdgcn_mfma_f32_16x16x32_bf16(ahi[rt], bhi[ci], acc[rt][ci], 0, 0, 0);
                acc[rt][ci] = __builtin_amdgcn_mfma_f32_16x16x32_bf16(alo[rt], bhi[ci], acc[rt][ci], 0, 0, 0);
                acc[rt][ci] = __builtin_amdgcn_mfma_f32_16x16x32_bf16(ahi[rt], blo[ci], acc[rt][ci], 0, 0, 0);
            }
    }

    // ---- epilogue: bias + relu + contract with W3, reduce over cols ----
    // acc element reg: row = lg*4 + reg (within 16-tile), col = cg (within tile)
    float pl[2][4] = {{0.f}}, rl[2][4] = {{0.f}};
#pragma unroll
    for (int rt = 0; rt < 2; ++rt)
#pragma unroll
        for (int ci = 0; ci < 2; ++ci) {
            const int col = w * 32 + ci * 16 + cg;
            const float bb = sb2[col], w3l = sW3l[col], w3r = sW3r[col];
#pragma unroll
            for (int reg = 0; reg < 4; ++reg) {
                float h2v = fmaxf(acc[rt][ci][reg] + bb, 0.f);
                pl[rt][reg] = fmaf(h2v, w3l, pl[rt][reg]);
                rl[rt][reg] = fmaf(h2v, w3r, rl[rt][reg]);
            }
        }
#pragma unroll
    for (int m = 8; m >= 1; m >>= 1)
#pragma unroll
        for (int rt = 0; rt < 2; ++rt)
#pragma unroll
            for (int reg = 0; reg < 4; ++reg) {
                pl[rt][reg] += __shfl_xor(pl[rt][reg], m, 64);
                rl[rt][reg] += __shfl_xor(rl[rt][reg], m, 64);
            }
    if (cg == 0) {
#pragma unroll
        for (int rt = 0; rt < 2; ++rt)
#pragma unroll
            for (int reg = 0; reg < 4; ++reg) {
                const int row = rt * 16 + lg * 4 + reg;
                sPP[w * 32 + row] = pl[rt][reg];
                sPR[w * 32 + row] = rl[rt][reg];
            }
    }
    __syncthreads();
    if (tid < 32) {
        float sp = sPP[tid] + sPP[32 + tid] + sPP[64 + tid] + sPP[96 + tid];
        float sr = sPR[tid] + sPR[32 + tid] + sPR[64 + tid] + sPR[96 + tid];
        p[node0 + tid] = sp;
        r[node0 + tid] = sr;
    }
}

// ---------------- output ----------------
__global__ void k_out(const int* __restrict__ rowptr, const int* __restrict__ csr,
                      const float* __restrict__ p, const float* __restrict__ r,
                      const float* __restrict__ deg_inv, const float* __restrict__ b3,
                      float* __restrict__ out) {
    int n = blockIdx.x * blockDim.x + threadIdx.x;
    if (n >= N) return;
    int lo = rowptr[n], hi = rowptr[n + 1];
    float a0 = 0.f, a1 = 0.f, a2 = 0.f, a3 = 0.f;
    int i = lo;
    for (; i + 3 < hi; i += 4) {
        a0 += p[csr[i]];
        a1 += p[csr[i + 1]];
        a2 += p[csr[i + 2]];
        a3 += p[csr[i + 3]];
    }
    for (; i < hi; ++i) a0 += p[csr[i]];
    out[n] = ((a0 + a1) + (a2 + a3)) * deg_inv[n] + r[n] + b3[0];
}

// ---------------- host ----------------
extern "C" void kernel_launch(void* const* d_in, const int* in_sizes, int n_in,
                              void* d_out, int out_size, void* d_ws, size_t ws_size,
                              hipStream_t stream) {
    const float* x    = (const float*)d_in[0];
    const int*   eidx = (const int*)d_in[1];   // [2,E] flat: row0=src, row1=dst
    const float* W1l  = (const float*)d_in[2];
    const float* W1r  = (const float*)d_in[3];
    const float* b1   = (const float*)d_in[4];
    const float* W2l  = (const float*)d_in[5];
    const float* W2r  = (const float*)d_in[6];
    const float* b2   = (const float*)d_in[7];
    const float* W3l  = (const float*)d_in[8];
    const float* W3r  = (const float*)d_in[9];
    const float* b3   = (const float*)d_in[10];
    float* out = (float*)d_out;

    const int* srcs = eidx;
    const int* dsts = eidx + E;

    size_t off = 0;
    auto alloc = [&](size_t bytes) {
        size_t o = off;
        off = (off + bytes + 255) & ~(size_t)255;
        return o;
    };
    char* w = (char*)d_ws;
    int*   deg_i   = (int*)(w + alloc((size_t)N * 4));
    int*   rowptr  = (int*)(w + alloc((size_t)(N + 1) * 4));
    int*   fillpos = (int*)(w + alloc((size_t)N * 4));
    int*   csr     = (int*)(w + alloc((size_t)E * 4));
    float* deg_inv = (float*)(w + alloc((size_t)N * 4));
    float* agg1    = (float*)(w + alloc((size_t)N * DIN * 4));
    float* h1      = (float*)(w + alloc((size_t)N * DH * 4));
    unsigned short* h1b = (unsigned short*)(w + alloc((size_t)N * DH * 2));
    float* agg2    = (float*)(w + alloc((size_t)N * DH * 4));
    float* pbuf    = (float*)(w + alloc((size_t)N * 4));
    float* rbuf    = (float*)(w + alloc((size_t)N * 4));
    int*   bsum    = (int*)(w + alloc((size_t)SCAN_BLOCKS * 4));
    unsigned short* Wthi = (unsigned short*)(w + alloc((size_t)DH * K2 * 2));
    unsigned short* Wtlo = (unsigned short*)(w + alloc((size_t)DH * K2 * 2));
    (void)ws_size;

    // 1. CSR build (parallel 3-phase scan)  + W2 prep (independent)
    k_zero_int<<<(N + 255) / 256, 256, 0, stream>>>(deg_i, N);
    k_prepw<<<(DH * K2 + 255) / 256, 256, 0, stream>>>(W2l, W2r, Wthi, Wtlo);
    k_degree<<<(E + 255) / 256, 256, 0, stream>>>(dsts, deg_i);
    k_block_sums<<<SCAN_BLOCKS, 256, 0, stream>>>(deg_i, bsum);
    k_scan_sums<<<1, 256, 0, stream>>>(bsum, SCAN_BLOCKS);
    k_emit<<<SCAN_BLOCKS, 256, 0, stream>>>(deg_i, bsum, rowptr, fillpos, deg_inv);
    k_fill<<<(E + 255) / 256, 256, 0, stream>>>(srcs, dsts, fillpos, csr);

    // 2. layer 1
    k_agg1<<<(N + 15) / 16, 256, 0, stream>>>(rowptr, csr, x, deg_inv, agg1);
    k_h1<<<1024, 256, 0, stream>>>(x, agg1, W1l, W1r, b1, h1, h1b);

    // 3. layer 2 aggregation (bf16 gather)
    k_agg2<<<(N + 3) / 4, 256, 0, stream>>>(rowptr, csr, (const unsigned int*)h1b,
                                            deg_inv, agg2);

    // 4. layer 2 GEMM + layer-3 projection (MFMA split-bf16)
    k_h2pr<<<N / 32, 256, 0, stream>>>(agg2, h1, Wthi, Wtlo, b2, W3l, W3r,
                                       pbuf, rbuf);

    // 5. output: scalar aggregation of p
    k_out<<<(N + 255) / 256, 256, 0, stream>>>(rowptr, csr, pbuf, rbuf, deg_inv, b3, out);
}

// Round 5
// 305.313 us; speedup vs baseline: 3.0449x; 1.3814x over previous
//
#include <hip/hip_runtime.h>
#include <hip/hip_bf16.h>

constexpr int N = 100000;      // nodes
constexpr int E = 1600000;     // edges
constexpr int DIN = 15;
constexpr int DH  = 128;
constexpr int K2  = 256;       // layer-2 GEMM K = DH (agg2) + DH (h1)

// bucketed CSR build
constexpr int CHUNK     = 8192;                    // edges per pass-1 block
constexpr int NBLK_P1   = (E + CHUNK - 1) / CHUNK; // 196
constexpr int BKT_NODES = 512;                     // nodes per bucket
constexpr int NBKT      = (N + BKT_NODES - 1) / BKT_NODES; // 196
constexpr int LREC_CAP  = 16384;                   // k_p2 LDS record capacity

typedef short short8 __attribute__((ext_vector_type(8)));
typedef float f32x4  __attribute__((ext_vector_type(4)));

__device__ __forceinline__ unsigned short f2bf_rne(float f) {
    unsigned u = __float_as_uint(f);
    u += 0x7fffu + ((u >> 16) & 1u);
    return (unsigned short)(u >> 16);
}
__device__ __forceinline__ float bf2f(unsigned short h) {
    return __uint_as_float(((unsigned)h) << 16);
}

// ---------------- CSR build: pass 1 (per-block counting sort into buckets) ----
// record = (local_dst << 17) | src ;  local_dst = dst & 511, bucket = dst >> 9
__global__ __launch_bounds__(256) void k_p1(const int* __restrict__ src,
                                            const int* __restrict__ dst,
                                            unsigned int* __restrict__ bsorted,
                                            int* __restrict__ offg) {
    __shared__ int hist[256];
    __shared__ int scn[256];
    __shared__ int fill[256];
    __shared__ unsigned int srt[CHUNK];   // 32 KB
    const int t   = threadIdx.x;
    const int blk = blockIdx.x;
    const int e0  = blk * CHUNK;
    hist[t] = 0;
    __syncthreads();
#pragma unroll
    for (int j = 0; j < CHUNK / 256; ++j) {
        int i = e0 + t + j * 256;
        if (i < E) atomicAdd(&hist[dst[i] >> 9], 1);
    }
    __syncthreads();
    scn[t] = hist[t];
    __syncthreads();
    for (int d = 1; d < 256; d <<= 1) {
        int v = (t >= d) ? scn[t - d] : 0;
        __syncthreads();
        scn[t] += v;
        __syncthreads();
    }
    int excl = (t == 0) ? 0 : scn[t - 1];
    fill[t] = excl;
    if (t < NBKT) offg[blk * (NBKT + 1) + t] = excl;
    if (t == 0)   offg[blk * (NBKT + 1) + NBKT] = scn[NBKT - 1];
    __syncthreads();
#pragma unroll
    for (int j = 0; j < CHUNK / 256; ++j) {
        int i = e0 + t + j * 256;
        if (i < E) {
            int dv = dst[i];
            int b  = dv >> 9;
            int pos = atomicAdd(&fill[b], 1);
            srt[pos] = ((unsigned)(dv & 511) << 17) | (unsigned)src[i];
        }
    }
    __syncthreads();
    for (int i = t; i < CHUNK; i += 256) bsorted[e0 + i] = srt[i];
}

// ---------------- CSR build: bucket starts (prefix over column sums) ---------
__global__ __launch_bounds__(256) void k_bstart(const int* __restrict__ offg,
                                                int* __restrict__ bstart) {
    __shared__ int tot[256];
    const int t = threadIdx.x;
    int s = 0;
    if (t < NBKT) {
        for (int blk = 0; blk < NBLK_P1; ++blk)
            s += offg[blk * (NBKT + 1) + t + 1] - offg[blk * (NBKT + 1) + t];
    }
    tot[t] = s;
    __syncthreads();
    for (int d = 1; d < 256; d <<= 1) {
        int v = (t >= d) ? tot[t - d] : 0;
        __syncthreads();
        tot[t] += v;
        __syncthreads();
    }
    if (t < NBKT) bstart[t] = (t == 0) ? 0 : tot[t - 1];
    if (t == 0)   bstart[NBKT] = tot[NBKT - 1];
}

// ---------------- CSR build: pass 2 (per-bucket fill, private csr window) ----
__global__ __launch_bounds__(256) void k_p2(const unsigned int* __restrict__ bsorted,
                                            const int* __restrict__ offg,
                                            const int* __restrict__ bstart,
                                            int* __restrict__ csr,
                                            int* __restrict__ rowptr,
                                            float* __restrict__ deg_inv) {
    __shared__ unsigned int lrec[LREC_CAP];    // 64 KB
    __shared__ int cum[NBLK_P1 + 1];
    __shared__ int runstart[NBLK_P1];
    __shared__ int ldeg[BKT_NODES];
    __shared__ int lrp[BKT_NODES];
    __shared__ int lfill[BKT_NODES];
    __shared__ int pscan[256];

    const int b = blockIdx.x;
    const int t = threadIdx.x;

    int cnt_blk = 0;
    if (t < NBLK_P1) {
        int o0 = offg[t * (NBKT + 1) + b];
        cnt_blk = offg[t * (NBKT + 1) + b + 1] - o0;
        runstart[t] = o0;
    }
    pscan[t] = cnt_blk;
    __syncthreads();
    for (int d = 1; d < 256; d <<= 1) {
        int v = (t >= d) ? pscan[t - d] : 0;
        __syncthreads();
        pscan[t] += v;
        __syncthreads();
    }
    if (t < NBLK_P1) cum[t] = (t == 0) ? 0 : pscan[t - 1];
    if (t == 0) cum[NBLK_P1] = pscan[NBLK_P1 - 1];
    ldeg[t] = 0;
    ldeg[t + 256] = 0;
    __syncthreads();

    int total = cum[NBLK_P1];
    if (total > LREC_CAP) total = LREC_CAP;   // statistically unreachable guard

    // gather records: binary search run for each record index (pipelined loads)
    for (int i = t; i < total; i += 256) {
        int lo = 0, hi = NBLK_P1;
        while (hi - lo > 1) {
            int mid = (lo + hi) >> 1;
            if (cum[mid] <= i) lo = mid; else hi = mid;
        }
        lrec[i] = bsorted[lo * CHUNK + runstart[lo] + (i - cum[lo])];
    }
    __syncthreads();

    // local degree histogram
    for (int i = t; i < total; i += 256) atomicAdd(&ldeg[lrec[i] >> 17], 1);
    __syncthreads();

    // exclusive scan of 512 degrees (pair-compress to 256)
    int p0 = ldeg[2 * t], p1 = ldeg[2 * t + 1];
    pscan[t] = p0 + p1;
    __syncthreads();
    for (int d = 1; d < 256; d <<= 1) {
        int v = (t >= d) ? pscan[t - d] : 0;
        __syncthreads();
        pscan[t] += v;
        __syncthreads();
    }
    int pairbase = (t == 0) ? 0 : pscan[t - 1];
    lrp[2 * t]     = pairbase;
    lrp[2 * t + 1] = pairbase + p0;
    lfill[2 * t] = 0;
    lfill[2 * t + 1] = 0;
    __syncthreads();

    const int bs = bstart[b];
    // scatter src into private contiguous csr window
    for (int i = t; i < total; i += 256) {
        unsigned rec = lrec[i];
        int ld  = rec >> 17;
        int pos = lrp[ld] + atomicAdd(&lfill[ld], 1);
        csr[bs + pos] = (int)(rec & 0x1ffff);
    }
    // rowptr + deg_inv
    for (int i = t; i < BKT_NODES; i += 256) {
        int g = b * BKT_NODES + i;
        if (g < N) {
            rowptr[g]  = bs + lrp[i];
            deg_inv[g] = 1.0f / fmaxf((float)ldeg[i], 1.0f);
        }
    }
    if (b == NBKT - 1 && t == 0) rowptr[N] = E;
}

// ---------------- layer 1 ----------------
__global__ __launch_bounds__(256) void k_agg1(const int* __restrict__ rowptr,
                                              const int* __restrict__ csr,
                                              const float* __restrict__ x,
                                              const float* __restrict__ deg_inv,
                                              float* __restrict__ agg1) {
    int g = threadIdx.x >> 4;        // 16 rows per block
    int d = threadIdx.x & 15;
    int n = blockIdx.x * 16 + g;
    if (n >= N || d >= DIN) return;
    int lo = rowptr[n], hi = rowptr[n + 1];
    float a0 = 0.f, a1 = 0.f, a2 = 0.f, a3 = 0.f;
    int i = lo;
    for (; i + 3 < hi; i += 4) {
        int s0 = csr[i], s1 = csr[i + 1], s2 = csr[i + 2], s3 = csr[i + 3];
        a0 += x[s0 * DIN + d];
        a1 += x[s1 * DIN + d];
        a2 += x[s2 * DIN + d];
        a3 += x[s3 * DIN + d];
    }
    for (; i < hi; ++i) a0 += x[csr[i] * DIN + d];
    agg1[n * DIN + d] = ((a0 + a1) + (a2 + a3)) * deg_inv[n];
}

__global__ __launch_bounds__(256) void k_h1(const float* __restrict__ x,
                                            const float* __restrict__ agg1,
                                            const float* __restrict__ W1l,
                                            const float* __restrict__ W1r,
                                            const float* __restrict__ b1,
                                            float* __restrict__ h1,
                                            unsigned short* __restrict__ h1b) {
    __shared__ float sWl[DIN * DH];
    __shared__ float sWr[DIN * DH];
    __shared__ float sb[DH];
    for (int i = threadIdx.x; i < DIN * DH; i += 256) {
        sWl[i] = W1l[i];
        sWr[i] = W1r[i];
    }
    if (threadIdx.x < DH) sb[threadIdx.x] = b1[threadIdx.x];
    __syncthreads();
    int j = threadIdx.x & 127;
    for (int n = blockIdx.x * 2 + (threadIdx.x >> 7); n < N; n += gridDim.x * 2) {
        const float* ar = &agg1[n * DIN];
        const float* xr = &x[n * DIN];
        float acc = sb[j];
#pragma unroll
        for (int k = 0; k < DIN; ++k)
            acc = fmaf(ar[k], sWl[k * DH + j], fmaf(xr[k], sWr[k * DH + j], acc));
        float v = fmaxf(acc, 0.f);
        h1[n * DH + j]  = v;
        h1b[n * DH + j] = f2bf_rne(v);
    }
}

// ---------------- layer 2 aggregation (SpMM, bf16 gather) ----------------
__global__ __launch_bounds__(256) void k_agg2(const int* __restrict__ rowptr,
                                              const int* __restrict__ csr,
                                              const unsigned int* __restrict__ h1b,
                                              const float* __restrict__ deg_inv,
                                              float* __restrict__ agg2) {
    const int lane = threadIdx.x & 63;
    const int n = blockIdx.x * 4 + (threadIdx.x >> 6);
    if (n >= N) return;
    const int lo = rowptr[n], hi = rowptr[n + 1];
    float a0x = 0.f, a0y = 0.f, a1x = 0.f, a1y = 0.f;
    float a2x = 0.f, a2y = 0.f, a3x = 0.f, a3y = 0.f;
    int i = lo;
    for (; i + 3 < hi; i += 4) {
        int s0 = csr[i], s1 = csr[i + 1], s2 = csr[i + 2], s3 = csr[i + 3];
        unsigned u0 = h1b[s0 * 64 + lane];
        unsigned u1 = h1b[s1 * 64 + lane];
        unsigned u2 = h1b[s2 * 64 + lane];
        unsigned u3 = h1b[s3 * 64 + lane];
        a0x += __uint_as_float(u0 << 16); a0y += __uint_as_float(u0 & 0xffff0000u);
        a1x += __uint_as_float(u1 << 16); a1y += __uint_as_float(u1 & 0xffff0000u);
        a2x += __uint_as_float(u2 << 16); a2y += __uint_as_float(u2 & 0xffff0000u);
        a3x += __uint_as_float(u3 << 16); a3y += __uint_as_float(u3 & 0xffff0000u);
    }
    for (; i < hi; ++i) {
        unsigned u = h1b[csr[i] * 64 + lane];
        a0x += __uint_as_float(u << 16); a0y += __uint_as_float(u & 0xffff0000u);
    }
    const float di = deg_inv[n];
    float2 r;
    r.x = ((a0x + a1x) + (a2x + a3x)) * di;
    r.y = ((a0y + a1y) + (a2y + a3y)) * di;
    ((float2*)agg2)[n * 64 + lane] = r;
}

// ---------------- W2 prep: transpose + hi/lo bf16 split ----------------
__global__ __launch_bounds__(256) void k_prepw(const float* __restrict__ W2l,
                                               const float* __restrict__ W2r,
                                               unsigned short* __restrict__ Wthi,
                                               unsigned short* __restrict__ Wtlo) {
    int id = blockIdx.x * 256 + threadIdx.x;       // 128 cols * 256 k
    if (id >= DH * K2) return;
    int col = id & 127;
    int k   = id >> 7;
    float wv = (k < DH) ? W2l[k * DH + col] : W2r[(k - DH) * DH + col];
    unsigned short hi = f2bf_rne(wv);
    unsigned short lo = f2bf_rne(wv - bf2f(hi));
    Wthi[col * K2 + k] = hi;
    Wtlo[col * K2 + k] = lo;
}

// ---------------- layer 2 GEMM + layer 3 projection (MFMA, split-bf16) ------
__global__ __launch_bounds__(256) void k_h2pr(const float* __restrict__ agg2,
                                              const float* __restrict__ h1,
                                              const unsigned short* __restrict__ Wthi,
                                              const unsigned short* __restrict__ Wtlo,
                                              const float* __restrict__ b2,
                                              const float* __restrict__ W3l,
                                              const float* __restrict__ W3r,
                                              float* __restrict__ p,
                                              float* __restrict__ r) {
    __shared__ __align__(16) unsigned short sAhi[32 * 32 * 8];   // 16 KB
    __shared__ __align__(16) unsigned short sAlo[32 * 32 * 8];   // 16 KB
    __shared__ float sb2[DH], sW3l[DH], sW3r[DH];
    __shared__ float sPP[4 * 32], sPR[4 * 32];

    const int tid   = threadIdx.x;
    const int node0 = blockIdx.x * 32;

    if (tid < DH) {
        sb2[tid]  = b2[tid];
        sW3l[tid] = W3l[tid];
        sW3r[tid] = W3r[tid];
    }

    {
        const int c = tid & 31;
        const int nb = tid >> 5;
#pragma unroll
        for (int it = 0; it < 4; ++it) {
            const int n = nb + it * 8;
            const int row = node0 + n;
            const float* src = (c < 16) ? &agg2[row * DH + c * 8]
                                        : &h1[row * DH + (c - 16) * 8];
            float4 v0 = *(const float4*)src;
            float4 v1 = *(const float4*)(src + 4);
            float v[8] = {v0.x, v0.y, v0.z, v0.w, v1.x, v1.y, v1.z, v1.w};
            unsigned hs[8], ls[8];
#pragma unroll
            for (int j = 0; j < 8; ++j) {
                unsigned short h = f2bf_rne(v[j]);
                unsigned short l2 = f2bf_rne(v[j] - bf2f(h));
                hs[j] = h; ls[j] = l2;
            }
            const int idx = (c * 32 + (n ^ (c & 7))) * 8;
            uint4 uh = {hs[0] | (hs[1] << 16), hs[2] | (hs[3] << 16),
                        hs[4] | (hs[5] << 16), hs[6] | (hs[7] << 16)};
            uint4 ul = {ls[0] | (ls[1] << 16), ls[2] | (ls[3] << 16),
                        ls[4] | (ls[5] << 16), ls[6] | (ls[7] << 16)};
            *(uint4*)&sAhi[idx] = uh;
            *(uint4*)&sAlo[idx] = ul;
        }
    }
    __syncthreads();

    const int w    = tid >> 6;
    const int lane = tid & 63;
    const int cg   = lane & 15;
    const int lg   = lane >> 4;

    f32x4 acc[2][2];
#pragma unroll
    for (int a = 0; a < 2; ++a)
#pragma unroll
        for (int b = 0; b < 2; ++b)
            acc[a][b] = (f32x4){0.f, 0.f, 0.f, 0.f};

    const unsigned short* bhp0 = &Wthi[(w * 32 + 0 * 16 + cg) * K2 + lg * 8];
    const unsigned short* bhp1 = &Wthi[(w * 32 + 1 * 16 + cg) * K2 + lg * 8];
    const unsigned short* blp0 = &Wtlo[(w * 32 + 0 * 16 + cg) * K2 + lg * 8];
    const unsigned short* blp1 = &Wtlo[(w * 32 + 1 * 16 + cg) * K2 + lg * 8];

#pragma unroll
    for (int s = 0; s < 8; ++s) {
        short8 ahi[2], alo[2];
#pragma unroll
        for (int rt = 0; rt < 2; ++rt) {
            const int c = s * 4 + lg;
            const int n = rt * 16 + cg;
            const int idx = (c * 32 + (n ^ (c & 7))) * 8;
            ahi[rt] = *(const short8*)&sAhi[idx];
            alo[rt] = *(const short8*)&sAlo[idx];
        }
        short8 bhi[2], blo[2];
        bhi[0] = *(const short8*)(bhp0 + s * 32);
        bhi[1] = *(const short8*)(bhp1 + s * 32);
        blo[0] = *(const short8*)(blp0 + s * 32);
        blo[1] = *(const short8*)(blp1 + s * 32);
#pragma unroll
        for (int rt = 0; rt < 2; ++rt)
#pragma unroll
            for (int ci = 0; ci < 2; ++ci) {
                acc[rt][ci] = __builtin_amdgcn_mfma_f32_16x16x32_bf16(ahi[rt], bhi[ci], acc[rt][ci], 0, 0, 0);
                acc[rt][ci] = __builtin_amdgcn_mfma_f32_16x16x32_bf16(alo[rt], bhi[ci], acc[rt][ci], 0, 0, 0);
                acc[rt][ci] = __builtin_amdgcn_mfma_f32_16x16x32_bf16(ahi[rt], blo[ci], acc[rt][ci], 0, 0, 0);
            }
    }

    float pl[2][4] = {{0.f}}, rl[2][4] = {{0.f}};
#pragma unroll
    for (int rt = 0; rt < 2; ++rt)
#pragma unroll
        for (int ci = 0; ci < 2; ++ci) {
            const int col = w * 32 + ci * 16 + cg;
            const float bb = sb2[col], w3l = sW3l[col], w3r = sW3r[col];
#pragma unroll
            for (int reg = 0; reg < 4; ++reg) {
                float h2v = fmaxf(acc[rt][ci][reg] + bb, 0.f);
                pl[rt][reg] = fmaf(h2v, w3l, pl[rt][reg]);
                rl[rt][reg] = fmaf(h2v, w3r, rl[rt][reg]);
            }
        }
#pragma unroll
    for (int m = 8; m >= 1; m >>= 1)
#pragma unroll
        for (int rt = 0; rt < 2; ++rt)
#pragma unroll
            for (int reg = 0; reg < 4; ++reg) {
                pl[rt][reg] += __shfl_xor(pl[rt][reg], m, 64);
                rl[rt][reg] += __shfl_xor(rl[rt][reg], m, 64);
            }
    if (cg == 0) {
#pragma unroll
        for (int rt = 0; rt < 2; ++rt)
#pragma unroll
            for (int reg = 0; reg < 4; ++reg) {
                const int row = rt * 16 + lg * 4 + reg;
                sPP[w * 32 + row] = pl[rt][reg];
                sPR[w * 32 + row] = rl[rt][reg];
            }
    }
    __syncthreads();
    if (tid < 32) {
        float sp = sPP[tid] + sPP[32 + tid] + sPP[64 + tid] + sPP[96 + tid];
        float sr = sPR[tid] + sPR[32 + tid] + sPR[64 + tid] + sPR[96 + tid];
        p[node0 + tid] = sp;
        r[node0 + tid] = sr;
    }
}

// ---------------- output ----------------
__global__ void k_out(const int* __restrict__ rowptr, const int* __restrict__ csr,
                      const float* __restrict__ p, const float* __restrict__ r,
                      const float* __restrict__ deg_inv, const float* __restrict__ b3,
                      float* __restrict__ out) {
    int n = blockIdx.x * blockDim.x + threadIdx.x;
    if (n >= N) return;
    int lo = rowptr[n], hi = rowptr[n + 1];
    float a0 = 0.f, a1 = 0.f, a2 = 0.f, a3 = 0.f;
    int i = lo;
    for (; i + 3 < hi; i += 4) {
        a0 += p[csr[i]];
        a1 += p[csr[i + 1]];
        a2 += p[csr[i + 2]];
        a3 += p[csr[i + 3]];
    }
    for (; i < hi; ++i) a0 += p[csr[i]];
    out[n] = ((a0 + a1) + (a2 + a3)) * deg_inv[n] + r[n] + b3[0];
}

// ---------------- host ----------------
extern "C" void kernel_launch(void* const* d_in, const int* in_sizes, int n_in,
                              void* d_out, int out_size, void* d_ws, size_t ws_size,
                              hipStream_t stream) {
    const float* x    = (const float*)d_in[0];
    const int*   eidx = (const int*)d_in[1];   // [2,E] flat: row0=src, row1=dst
    const float* W1l  = (const float*)d_in[2];
    const float* W1r  = (const float*)d_in[3];
    const float* b1   = (const float*)d_in[4];
    const float* W2l  = (const float*)d_in[5];
    const float* W2r  = (const float*)d_in[6];
    const float* b2   = (const float*)d_in[7];
    const float* W3l  = (const float*)d_in[8];
    const float* W3r  = (const float*)d_in[9];
    const float* b3   = (const float*)d_in[10];
    float* out = (float*)d_out;

    const int* srcs = eidx;
    const int* dsts = eidx + E;

    size_t off = 0;
    auto alloc = [&](size_t bytes) {
        size_t o = off;
        off = (off + bytes + 255) & ~(size_t)255;
        return o;
    };
    char* w = (char*)d_ws;
    int*   rowptr  = (int*)(w + alloc((size_t)(N + 1) * 4));
    int*   csr     = (int*)(w + alloc((size_t)E * 4));
    float* deg_inv = (float*)(w + alloc((size_t)N * 4));
    float* agg1    = (float*)(w + alloc((size_t)N * DIN * 4));
    float* h1      = (float*)(w + alloc((size_t)N * DH * 4));
    unsigned short* h1b = (unsigned short*)(w + alloc((size_t)N * DH * 2));
    float* agg2    = (float*)(w + alloc((size_t)N * DH * 4));
    float* pbuf    = (float*)(w + alloc((size_t)N * 4));
    float* rbuf    = (float*)(w + alloc((size_t)N * 4));
    unsigned short* Wthi = (unsigned short*)(w + alloc((size_t)DH * K2 * 2));
    unsigned short* Wtlo = (unsigned short*)(w + alloc((size_t)DH * K2 * 2));
    unsigned int* bsorted = (unsigned int*)(w + alloc((size_t)NBLK_P1 * CHUNK * 4));
    int*   offg    = (int*)(w + alloc((size_t)NBLK_P1 * (NBKT + 1) * 4));
    int*   bstart  = (int*)(w + alloc((size_t)(NBKT + 1) * 4));
    (void)ws_size;

    // 1. CSR build (bucketed counting sort; no global atomics) + W2 prep
    k_prepw<<<(DH * K2 + 255) / 256, 256, 0, stream>>>(W2l, W2r, Wthi, Wtlo);
    k_p1<<<NBLK_P1, 256, 0, stream>>>(srcs, dsts, bsorted, offg);
    k_bstart<<<1, 256, 0, stream>>>(offg, bstart);
    k_p2<<<NBKT, 256, 0, stream>>>(bsorted, offg, bstart, csr, rowptr, deg_inv);

    // 2. layer 1
    k_agg1<<<(N + 15) / 16, 256, 0, stream>>>(rowptr, csr, x, deg_inv, agg1);
    k_h1<<<1024, 256, 0, stream>>>(x, agg1, W1l, W1r, b1, h1, h1b);

    // 3. layer 2 aggregation (bf16 gather)
    k_agg2<<<(N + 3) / 4, 256, 0, stream>>>(rowptr, csr, (const unsigned int*)h1b,
                                            deg_inv, agg2);

    // 4. layer 2 GEMM + layer-3 projection (MFMA split-bf16)
    k_h2pr<<<N / 32, 256, 0, stream>>>(agg2, h1, Wthi, Wtlo, b2, W3l, W3r,
                                       pbuf, rbuf);

    // 5. output: scalar aggregation of p
    k_out<<<(N + 255) / 256, 256, 0, stream>>>(rowptr, csr, pbuf, rbuf, deg_inv, b3, out);
}